// Round 3
// baseline (44.812 us; speedup 1.0000x reference)
//
#include <hip/hip_runtime.h>
#include <math.h>

// dist[b,n] = sum_d softplus(fw[d]) * |q[b,d] - X[n,d]|
//           = sum_d |wq[b,d] - ws[d]*X[n,d]|,  wq = ws*q, ws = softplus(fw) > 0
//
// Round 3: q moved from LDS to the SCALAR path (pre-kernel writes wq to d_ws;
// main kernel reads it with wave-uniform indices -> s_load, zero LDS traffic).
// X staged per-wave (barrier-free), XOR-swizzled LDS, 4 acc chains.

constexpr int D = 64;
constexpr int BCHUNK = 16;   // b-values per block
constexpr int NT = 128;      // threads/block (2 waves)
constexpr int ROWS = 128;    // X rows per block (1 per thread)

// ---- Kernel A: wq[b][d] = softplus(fw[d]) * q[b][d]; ws appended after ----
__global__ void prep_kernel(const float* __restrict__ q,
                            const float* __restrict__ fw,
                            float* __restrict__ wq, int B) {
    __shared__ float ws[D];
    const int t = threadIdx.x;
    if (t < D) {
        float x = fw[t];
        float w = fmaxf(x, 0.f) + log1pf(expf(-fabsf(x)));  // stable softplus
        ws[t] = w;
        wq[B * D + t] = w;
    }
    __syncthreads();
    for (int i = t; i < B * D; i += blockDim.x)
        wq[i] = ws[i & (D - 1)] * q[i];
}

// ---- Kernel B: main distance kernel ----
__global__ __launch_bounds__(NT, 4)
void fdist_kernel(const float* __restrict__ X,
                  const float* __restrict__ wq,
                  float* __restrict__ out, int N, int wsoff4) {
    __shared__ float4 xq[ROWS * 16];

    const int t = threadIdx.x;
    const int wave = t >> 6;
    const int lane = t & 63;

    // bijective XCD-chunked swizzle (m204), then x-outer / y-inner decode
    const int nwg = gridDim.x;
    const int orig = blockIdx.x;
    const int q8 = nwg >> 3, r8 = nwg & 7;
    const int xcd = orig & 7, pos = orig >> 3;
    const int wg = (xcd < r8 ? xcd * (q8 + 1) : r8 * (q8 + 1) + (xcd - r8) * q8) + pos;
    const int xb = wg >> 2;                 // consecutive wg on one XCD share X slice
    const int bbase = (wg & 3) * BCHUNK;
    const int nbase = xb * ROWS;

    const int rsub = lane >> 4;             // 0..3
    const int col = lane & 15;              // float4 column within a row
    const float4* Xv = reinterpret_cast<const float4*>(X);
    const float4* wq4 = reinterpret_cast<const float4*>(wq);

    // per-lane column weights (ws), one 16B load from L2
    const float4 wv = wq4[wsoff4 + col];

    // ---- per-wave staging of its own 64 rows: coalesced, scaled, swizzled ----
#pragma unroll
    for (int j = 0; j < 16; ++j) {
        const int r = j * 4 + rsub;                  // row within wave's 64
        int grow = nbase + wave * 64 + r;
        grow = grow < N ? grow : N - 1;
        float4 v = Xv[(size_t)grow * 16 + col];
        v.x *= wv.x; v.y *= wv.y; v.z *= wv.z; v.w *= wv.w;
        xq[(wave * 64 + r) * 16 + (col ^ (r & 7))] = v;
    }
    // wave-local: own lanes' ds_writes must land before cross-lane ds_reads.
    asm volatile("s_waitcnt vmcnt(0) lgkmcnt(0)" ::: "memory");

    float4 xs[16];
#pragma unroll
    for (int i = 0; i < 16; ++i)
        xs[i] = xq[(wave * 64 + lane) * 16 + (i ^ (lane & 7))];

    const int n = nbase + wave * 64 + lane;

    // ---- main loop: q rows via wave-uniform (scalar) loads, 4 acc chains ----
#pragma unroll 4
    for (int bi = 0; bi < BCHUNK; ++bi) {
        const float4* qrow = wq4 + (size_t)(bbase + bi) * 16;
        float ax = 0.f, ay = 0.f, az = 0.f, aw = 0.f;
#pragma unroll
        for (int i = 0; i < 16; ++i) {
            const float4 qv = qrow[i];               // uniform -> s_load
            ax += fabsf(qv.x - xs[i].x);
            ay += fabsf(qv.y - xs[i].y);
            az += fabsf(qv.z - xs[i].z);
            aw += fabsf(qv.w - xs[i].w);
        }
        if (n < N) out[(size_t)(bbase + bi) * N + n] = (ax + ay) + (az + aw);
    }
}

extern "C" void kernel_launch(void* const* d_in, const int* in_sizes, int n_in,
                              void* d_out, int out_size, void* d_ws, size_t ws_size,
                              hipStream_t stream) {
    const float* q  = (const float*)d_in[0];
    const float* X  = (const float*)d_in[1];
    const float* fw = (const float*)d_in[2];
    float* out = (float*)d_out;
    float* wq = (float*)d_ws;

    const int B = in_sizes[0] / D;  // 64
    const int N = in_sizes[1] / D;  // 50000

    prep_kernel<<<dim3(1), dim3(256), 0, stream>>>(q, fw, wq, B);

    const int nxblk = (N + ROWS - 1) / ROWS;          // 391
    const int nwg = nxblk * (B / BCHUNK);             // 1564
    fdist_kernel<<<dim3(nwg), dim3(NT), 0, stream>>>(X, wq, out, N, B * D / 4);
}

// Round 4
// 31.830 us; speedup vs baseline: 1.4079x; 1.4079x over previous
//
#include <hip/hip_runtime.h>
#include <math.h>

// dist[b,n] = sum_d softplus(fw[d]) * |q[b,d] - X[n,d]|
//           = sum_d |wq[b,d] - ws[d]*X[n,d]|,  wq = ws*q, ws = softplus(fw) > 0
//
// Round 4: scalar-q done right. prep writes wq+ws to d_ws; main kernel reads q
// rows via wave-uniform s_load (SGPR operands feed v_sub_f32 directly, zero
// LDS/VMEM/VGPR cost for q). X rows live in 64 VGPRs, loaded coalesced and
// transposed through small per-wave LDS half-buffers (barrier-free, PAD=68
// even-bank-spread). 34 KB LDS + <=128 VGPR -> 16 waves/CU to hide SMEM
// latency (round 3 failed at 4 waves/CU). Inner loop: no DS ops at all.

constexpr int D = 64;
constexpr int BCHUNK = 16;   // b-values per block
constexpr int NT = 256;      // 4 waves
constexpr int ROWS = 256;    // X rows per block (1 per thread)
constexpr int PADF = 68;     // LDS row stride in floats: 4*(r+col) bank spread

// ---- Kernel A: wq[b][d] = softplus(fw[d]) * q[b][d]; ws appended ----
__global__ void prep_kernel(const float* __restrict__ q,
                            const float* __restrict__ fw,
                            float* __restrict__ wq, int B) {
    __shared__ float ws[D];
    const int t = threadIdx.x;
    if (t < D) {
        float x = fw[t];
        float w = fmaxf(x, 0.f) + log1pf(expf(-fabsf(x)));  // stable softplus
        ws[t] = w;
        wq[B * D + t] = w;
    }
    __syncthreads();
    for (int i = t; i < B * D; i += blockDim.x)
        wq[i] = ws[i & (D - 1)] * q[i];
}

// ---- Kernel B: main distance kernel ----
__global__ __launch_bounds__(NT, 4)
void fdist_kernel(const float* __restrict__ X,
                  const float* __restrict__ wq,
                  float* __restrict__ out, int N, int wsoff4) {
    __shared__ float xbuf[4][32 * PADF];   // per-wave transpose buffer, 8704 B

    const int t = threadIdx.x;
    const int wave = t >> 6;
    const int lane = t & 63;

    // bijective XCD swizzle (nwg divisible by 8), x-outer / y-inner decode
    const int nwg = gridDim.x;
    const int cpx = nwg >> 3;
    const int orig = blockIdx.x;
    const int wg = (orig & 7) * cpx + (orig >> 3);
    const int nbase = (wg >> 2) * ROWS;     // consecutive wg on an XCD share X
    const int bbase = (wg & 3) * BCHUNK;

    const int col = lane & 15;              // float4 column within a row
    const int rsub = lane >> 4;             // 0..3
    const float4* Xv = reinterpret_cast<const float4*>(X);
    const float4* wq4 = reinterpret_cast<const float4*>(wq);
    const float4 wv = wq4[wsoff4 + col];    // ws[col*4 .. col*4+3]

    float* wb = xbuf[wave];
    const int myphase = lane >> 5;          // which half stages my row
    const int lr = lane & 31;               // my row within the half-buffer

    // ---- transpose X through per-wave half-buffers (no __syncthreads) ----
    float4 xs[16];
#pragma unroll
    for (int k = 0; k < 2; ++k) {
        // stage local rows 0..31 = global rows [wave*64 + k*32, +32), coalesced
#pragma unroll
        for (int j = 0; j < 8; ++j) {
            const int r = j * 4 + rsub;                  // 0..31
            int grow = nbase + wave * 64 + k * 32 + r;
            grow = grow < N ? grow : N - 1;
            float4 v = Xv[(size_t)grow * 16 + col];
            v.x *= wv.x; v.y *= wv.y; v.z *= wv.z; v.w *= wv.w;
            *reinterpret_cast<float4*>(&wb[r * PADF + col * 4]) = v;
        }
        // same-wave cross-lane RAW on wb: compiler orders via lgkmcnt/vmcnt
        if (myphase == k) {
#pragma unroll
            for (int i = 0; i < 16; ++i)
                xs[i] = *reinterpret_cast<const float4*>(&wb[lr * PADF + i * 4]);
        }
    }

    const int n = nbase + t;
    const bool valid = n < N;

    // ---- main loop: q rows via s_load (uniform), X in regs, no DS ops ----
#pragma unroll 2
    for (int bi = 0; bi < BCHUNK; ++bi) {
        const float4* __restrict__ qrow = wq4 + (size_t)(bbase + bi) * 16;
        float a0 = 0.f, a1 = 0.f, a2 = 0.f, a3 = 0.f;
#pragma unroll
        for (int i = 0; i < 16; ++i) {
            const float4 qv = qrow[i];                   // uniform -> s_load
            a0 += fabsf(qv.x - xs[i].x);
            a1 += fabsf(qv.y - xs[i].y);
            a2 += fabsf(qv.z - xs[i].z);
            a3 += fabsf(qv.w - xs[i].w);
        }
        if (valid) out[(size_t)(bbase + bi) * N + n] = (a0 + a1) + (a2 + a3);
    }
}

extern "C" void kernel_launch(void* const* d_in, const int* in_sizes, int n_in,
                              void* d_out, int out_size, void* d_ws, size_t ws_size,
                              hipStream_t stream) {
    const float* q  = (const float*)d_in[0];
    const float* X  = (const float*)d_in[1];
    const float* fw = (const float*)d_in[2];
    float* out = (float*)d_out;
    float* wq = (float*)d_ws;

    const int B = in_sizes[0] / D;  // 64
    const int N = in_sizes[1] / D;  // 50000

    prep_kernel<<<dim3(1), dim3(256), 0, stream>>>(q, fw, wq, B);

    const int nxblk = (N + ROWS - 1) / ROWS;          // 196
    const int nwg = nxblk * (B / BCHUNK);             // 784 (divisible by 8)
    fdist_kernel<<<dim3(nwg), dim3(NT), 0, stream>>>(X, wq, out, N, B * D / 4);
}

// Round 5
// 23.397 us; speedup vs baseline: 1.9153x; 1.3604x over previous
//
#include <hip/hip_runtime.h>
#include <hip/hip_fp16.h>
#include <math.h>

// dist[b,n] = sum_d softplus(fw[d]) * |q[b,d] - X[n,d]|
//           = sum_d |wq[b,d] - wx[n,d]|,  wq = w*q, wx = w*X, w = softplus(fw) > 0
//
// Round 5: packed fp16 inner loop (v_pk_sub + v_and abs + v_pk_add = 3 instr
// per 2 elems -> VALU floor 3.9 us). q tile packed-scaled in LDS (row = 128 B
// -> 8 broadcast ds_read_b128 per bi feeding 192 VALU instrs: LDS pipe at
// parity with VALU instead of 3x over). X: 2 rows/thread in 64 VGPRs via
// barrier-free per-wave LDS transpose staging. Softplus folded in-block (no
// prep kernel). fp16 accumulate error ~0.3 << 2.86 threshold.

constexpr int D = 64;
constexpr int BCHUNK = 16;   // b-values per block
constexpr int NT = 256;      // 4 waves
constexpr int ROWS = 512;    // X rows per block (2 per thread)
constexpr int PADH = 72;     // LDS halfs per staged row (144 B stride)

__global__ __launch_bounds__(NT, 4)
void fdist_kernel(const float* __restrict__ q,
                  const float* __restrict__ X,
                  const float* __restrict__ fw,
                  float* __restrict__ out, int N) {
    __shared__ float ws[D];
    __shared__ __align__(16) __half qs[BCHUNK][D];       // 2 KB
    __shared__ __align__(16) __half xbuf[4][64 * PADH];  // 4 x 9216 B

    const int t = threadIdx.x;
    const int w = t >> 6, l = t & 63;

    // bijective XCD swizzle (nwg % 8 == 0), x-outer / y-inner decode
    const int nwg = gridDim.x, cpx = nwg >> 3;
    const int wg = (blockIdx.x & 7) * cpx + (blockIdx.x >> 3);
    const int nbase = (wg >> 2) * ROWS;
    const int bbase = (wg & 3) * BCHUNK;

    // softplus(fw) -> ws
    if (t < D) {
        float x = fw[t];
        ws[t] = fmaxf(x, 0.f) + log1pf(expf(-fabsf(x)));
    }
    __syncthreads();

    // ---- q tile: scaled + packed to fp16, [16][64] halfs (row = 128 B) ----
    const float2* q2 = reinterpret_cast<const float2*>(q);
#pragma unroll
    for (int k = 0; k < 2; ++k) {
        const int e = t + k * 256;                 // half2 index within tile
        const float2 v = q2[(size_t)bbase * 32 + e];
        const int d = (e & 31) * 2;                // d-index of first elem
        *reinterpret_cast<__half2*>(&qs[e >> 5][d]) =
            __floats2half2_rn(v.x * ws[d], v.y * ws[d + 1]);
    }

    // per-lane column weights for X staging
    const int col = l & 15, rsub = l >> 4;
    const float4 wv = {ws[col * 4], ws[col * 4 + 1], ws[col * 4 + 2], ws[col * 4 + 3]};

    // ---- X: per-wave barrier-free transpose staging, 2 parts of 64 rows ----
    __half* wb = xbuf[w];
    const float4* Xv = reinterpret_cast<const float4*>(X);
    __half2 xr[2][32];                             // 2 rows x 64 halfs in VGPRs

    union H4 { float4 f; __half2 h[4]; };
    union H2 { float2 f; __half2 h[2]; };

#pragma unroll
    for (int p = 0; p < 2; ++p) {
#pragma unroll
        for (int j = 0; j < 16; ++j) {
            const int r = j * 4 + rsub;            // 0..63
            int grow = nbase + w * 128 + p * 64 + r;
            grow = grow < N ? grow : N - 1;
            const float4 v = Xv[(size_t)grow * 16 + col];   // coalesced 1 KB/instr
            H2 u;
            u.h[0] = __floats2half2_rn(v.x * wv.x, v.y * wv.y);
            u.h[1] = __floats2half2_rn(v.z * wv.z, v.w * wv.w);
            *reinterpret_cast<float2*>(&wb[r * PADH + col * 4]) = u.f;
        }
        asm volatile("s_waitcnt lgkmcnt(0)" ::: "memory");  // wave-local RAW
#pragma unroll
        for (int i = 0; i < 8; ++i) {
            H4 u;
            u.f = *reinterpret_cast<const float4*>(&wb[l * PADH + i * 8]);
#pragma unroll
            for (int k = 0; k < 4; ++k) xr[p][i * 4 + k] = u.h[k];
        }
        asm volatile("s_waitcnt lgkmcnt(0)" ::: "memory");  // drain before restage
    }
    __syncthreads();   // qs visible to all waves

    const int nA = nbase + w * 128 + l;
    const int nB = nA + 64;
    const float4* qs4 = reinterpret_cast<const float4*>(qs);  // [16][8]

    // ---- main loop: 16 b-rows; q via broadcast ds_read_b128, X in VGPRs ----
#pragma unroll 2
    for (int bi = 0; bi < BCHUNK; ++bi) {
        const __half2 z = __float2half2_rn(0.f);
        __half2 a0 = z, a1 = z, b0 = z, b1 = z;
#pragma unroll
        for (int i = 0; i < 8; ++i) {
            H4 qv;
            qv.f = qs4[bi * 8 + i];                // uniform -> broadcast
#pragma unroll
            for (int k = 0; k < 4; ++k) {
                const __half2 dA = __habs2(__hsub2(qv.h[k], xr[0][i * 4 + k]));
                const __half2 dB = __habs2(__hsub2(qv.h[k], xr[1][i * 4 + k]));
                if (k & 1) { a1 = __hadd2(a1, dA); b1 = __hadd2(b1, dB); }
                else       { a0 = __hadd2(a0, dA); b0 = __hadd2(b0, dB); }
            }
        }
        const __half2 sa = __hadd2(a0, a1), sb = __hadd2(b0, b1);
        float* orow = out + (size_t)(bbase + bi) * N;
        if (nA < N) orow[nA] = __low2float(sa) + __high2float(sa);
        if (nB < N) orow[nB] = __low2float(sb) + __high2float(sb);
    }
}

extern "C" void kernel_launch(void* const* d_in, const int* in_sizes, int n_in,
                              void* d_out, int out_size, void* d_ws, size_t ws_size,
                              hipStream_t stream) {
    const float* q  = (const float*)d_in[0];
    const float* X  = (const float*)d_in[1];
    const float* fw = (const float*)d_in[2];
    float* out = (float*)d_out;

    const int B = in_sizes[0] / D;  // 64
    const int N = in_sizes[1] / D;  // 50000

    const int nxblk = (N + ROWS - 1) / ROWS;      // 98
    const int nwg = nxblk * (B / BCHUNK);         // 392 (divisible by 8)
    fdist_kernel<<<dim3(nwg), dim3(NT), 0, stream>>>(q, X, fw, out, N);
}